// Round 7
// baseline (324.935 us; speedup 1.0000x reference)
//
#include <hip/hip_runtime.h>
#include <hip/hip_bf16.h>
#include <math.h>
#include <stdint.h>

// Problem constants (B=2, S=2048 -> T=4096 tokens)
#define TOKENS 4096
#define HDIM   768
#define FFDIM  1536
#define NEXP   8
#define NCT    12     // col tiles: GEMM1 1536/128, GEMM2 768/64 (same count!)
#define WMAX   256    // max works per XCD bucket (overflow spills)

typedef __attribute__((ext_vector_type(8))) short bf16x8;   // 8 bf16 = 4 VGPRs
typedef __attribute__((ext_vector_type(4))) float f32x4;    // MFMA accumulator

// round-to-nearest-even f32 -> bf16 (bit pattern)
__device__ __forceinline__ unsigned short f2bf(float f) {
    union { float f; uint32_t u; } c; c.f = f;
    uint32_t u = c.u;
    uint32_t r = (u + 0x7FFFu + ((u >> 16) & 1u)) >> 16;
    return (unsigned short)r;
}

// async global->LDS, 16B per lane; LDS dest is wave-uniform base + lane*16
__device__ __forceinline__ void gload_lds16(const void* g, void* l) {
    __builtin_amdgcn_global_load_lds(
        (const __attribute__((address_space(1))) void*)g,
        (__attribute__((address_space(3))) void*)l, 16, 0, 0);
}

// ---------------------------------------------------------------------------
// both weight casts in one dispatch; n4 = float4 count of EACH tensor
__global__ void cast_bf16_2(const float* __restrict__ s1, unsigned short* __restrict__ d1,
                            const float* __restrict__ s2, unsigned short* __restrict__ d2,
                            int n4) {
    int stride = gridDim.x * blockDim.x;
    for (int i = blockIdx.x * blockDim.x + threadIdx.x; i < 2 * n4; i += stride) {
        const float4* s = (i < n4) ? (const float4*)s1 : (const float4*)s2;
        ushort4* d = (i < n4) ? (ushort4*)d1 : (ushort4*)d2;
        int j = (i < n4) ? i : i - n4;
        float4 v = s[j];
        ushort4 o;
        o.x = f2bf(v.x); o.y = f2bf(v.y); o.z = f2bf(v.z); o.w = f2bf(v.w);
        d[j] = o;
    }
}

// ---------------------------------------------------------------------------
// Gating: one wave per token (4 tokens / 256-thread block). fp32 logits
// (checked output!), top-2 softmax, no atomics. Fused: bf16 cast of x, and
// zeroing of outp (must precede GEMM2, which is stream-ordered after).
__global__ __launch_bounds__(256) void gating(
    const float* __restrict__ x, const float* __restrict__ gw,
    float* __restrict__ logits,
    int* __restrict__ tok_e, float* __restrict__ tok_g,
    unsigned short* __restrict__ x_bf, float* __restrict__ outp)
{
    // zero outp: 786432 float4 over 1024 blocks = 3 per thread
    float4 zz = make_float4(0.f, 0.f, 0.f, 0.f);
#pragma unroll
    for (int j = 0; j < 3; j++)
        ((float4*)outp)[blockIdx.x * 768 + j * 256 + threadIdx.x] = zz;

    int t = blockIdx.x * 4 + (threadIdx.x >> 6);
    int lane = threadIdx.x & 63;
    const float4* xt = (const float4*)(x + (size_t)t * HDIM);   // 192 float4/token
    const float4* gw4 = (const float4*)gw;                      // [E][192]
    ushort4* xbt = (ushort4*)(x_bf + (size_t)t * HDIM);
    float acc[NEXP];
#pragma unroll
    for (int e = 0; e < NEXP; e++) acc[e] = 0.f;
#pragma unroll
    for (int it = 0; it < 3; it++) {
        int i = lane + it * 64;
        float4 xv = xt[i];
        ushort4 o;
        o.x = f2bf(xv.x); o.y = f2bf(xv.y); o.z = f2bf(xv.z); o.w = f2bf(xv.w);
        xbt[i] = o;
#pragma unroll
        for (int e = 0; e < NEXP; e++) {
            float4 wv = gw4[e * 192 + i];
            acc[e] += xv.x * wv.x + xv.y * wv.y + xv.z * wv.z + xv.w * wv.w;
        }
    }
#pragma unroll
    for (int e = 0; e < NEXP; e++) {
#pragma unroll
        for (int off = 32; off > 0; off >>= 1)
            acc[e] += __shfl_xor(acc[e], off);
    }
    if (lane == 0) {
        float4 l0 = make_float4(acc[0], acc[1], acc[2], acc[3]);
        float4 l1 = make_float4(acc[4], acc[5], acc[6], acc[7]);
        float4* lp = (float4*)(logits + (size_t)t * NEXP);
        lp[0] = l0; lp[1] = l1;
        int i0 = 0; float v0 = acc[0];
#pragma unroll
        for (int e = 1; e < NEXP; e++) if (acc[e] > v0) { v0 = acc[e]; i0 = e; }
        int i1 = -1; float v1 = -3.4e38f;
#pragma unroll
        for (int e = 0; e < NEXP; e++) if (e != i0 && acc[e] > v1) { v1 = acc[e]; i1 = e; }
        float g0 = 1.f / (1.f + expf(v1 - v0));   // softmax over top-2 (v0 >= v1)
        tok_e[t * 2] = i0; tok_e[t * 2 + 1] = i1;
        tok_g[t * 2] = g0; tok_g[t * 2 + 1] = 1.f - g0;
    }
}

// ---------------------------------------------------------------------------
// Build per-expert routed lists deterministically (no global atomics).
// Single block, 1024 threads (16 waves), 8 (token,k) entries per thread.
// Per-wave __shfl_up u64 scan + 16-wave fixup (2 barriers total).
// Emits counts[e], bases[e], and the XCD-aware WORK TABLE: work[p*8 + b]
// = (ct<<20)|(e<<16)|row0 with bucket b = e, so (assuming round-robin
// block->XCD dispatch by linear id % 8) ALL blocks of expert e land on one
// XCD -> its B slice + A rows (~4-5.5 MB) stay L2-resident instead of being
// re-fetched by all 8 XCDs (r6: FETCH 122 MB vs 32 MB ideal). One table
// serves both GEMMs (both have 12 col tiles, 128-row tiles).
__global__ __launch_bounds__(1024) void build_lists(
    const int* __restrict__ tok_e, const float* __restrict__ tok_g,
    int* __restrict__ counts, int* __restrict__ bases,
    int* __restrict__ work,
    int* __restrict__ entries, float* __restrict__ gates)
{
    __shared__ unsigned long long wlo[16], whi[16];
    int tid = threadIdx.x;
    int lane = tid & 63, wid = tid >> 6;
    // init work table to sentinel (before first barrier; tid0 fills after it)
#pragma unroll
    for (int j = 0; j < (8 * WMAX) / 1024; j++) work[j * 1024 + tid] = -1;

    int eL[8]; float gL[8];
    int4 ea = ((const int4*)tok_e)[tid * 2];
    int4 eb = ((const int4*)tok_e)[tid * 2 + 1];
    float4 ga = ((const float4*)tok_g)[tid * 2];
    float4 gb = ((const float4*)tok_g)[tid * 2 + 1];
    eL[0] = ea.x; eL[1] = ea.y; eL[2] = ea.z; eL[3] = ea.w;
    eL[4] = eb.x; eL[5] = eb.y; eL[6] = eb.z; eL[7] = eb.w;
    gL[0] = ga.x; gL[1] = ga.y; gL[2] = ga.z; gL[3] = ga.w;
    gL[4] = gb.x; gL[5] = gb.y; gL[6] = gb.z; gL[7] = gb.w;

    unsigned long long clo = 0, chi = 0;
#pragma unroll
    for (int j = 0; j < 8; j++) {
        int e = eL[j];
        unsigned long long one = 1ull << ((e & 3) * 16);
        if (e < 4) clo += one; else chi += one;
    }
    unsigned long long ilo = clo, ihi = chi;
#pragma unroll
    for (int s = 1; s < 64; s <<= 1) {
        unsigned long long t1 = __shfl_up(ilo, s);
        unsigned long long t2 = __shfl_up(ihi, s);
        if (lane >= s) { ilo += t1; ihi += t2; }
    }
    if (lane == 63) { wlo[wid] = ilo; whi[wid] = ihi; }
    __syncthreads();
    if (tid == 0) {
        unsigned long long rl = 0, rh = 0;
#pragma unroll
        for (int i = 0; i < 16; i++) {
            unsigned long long a = wlo[i], b = whi[i];
            wlo[i] = rl; whi[i] = rh;   // exclusive wave prefix
            rl += a; rh += b;
        }
        int c[8];
#pragma unroll
        for (int e = 0; e < 4; e++) {
            c[e]     = (int)((rl >> (e * 16)) & 0xFFFF);
            c[e + 4] = (int)((rh >> (e * 16)) & 0xFFFF);
        }
        int b = 0;
        int blen[8];
#pragma unroll
        for (int e = 0; e < NEXP; e++) { counts[e] = c[e]; bases[e] = b; b += c[e]; blen[e] = 0; }
        for (int e = 0; e < NEXP; e++) {
            int rts = (c[e] + 127) >> 7;
            for (int ct = 0; ct < NCT; ct++) {
                for (int r = 0; r < rts; r++) {
                    int bk = e;
                    if (blen[bk] >= WMAX) {       // overflow: spill to shortest
                        int mn = 0x7FFFFFFF;
                        for (int k = 0; k < 8; k++) if (blen[k] < mn) { mn = blen[k]; bk = k; }
                    }
                    work[blen[bk] * 8 + bk] = (ct << 20) | (e << 16) | (r << 7);
                    blen[bk]++;
                }
            }
        }
    }
    __syncthreads();
    unsigned long long rlo = wlo[wid] + (ilo - clo);   // exclusive thread prefix
    unsigned long long rhi = whi[wid] + (ihi - chi);
#pragma unroll
    for (int j = 0; j < 8; j++) {
        int e = eL[j];
        int sh = (e & 3) * 16;
        unsigned long long one = 1ull << sh;
        int slot;
        if (e < 4) { slot = (int)((rlo >> sh) & 0xFFFF); rlo += one; }
        else       { slot = (int)((rhi >> sh) & 0xFFFF); rhi += one; }
        entries[e * TOKENS + slot] = tid * 8 + j;   // = t*2+k
        gates[e * TOKENS + slot]   = gL[j];
    }
}

// ---------------------------------------------------------------------------
// Routed GEMM, 128xTN tile, BK=64, single-buffer 2-barrier K-loop (r5 dbuf
// regressed: dynamic buffer index defeats LDS alias analysis -> early
// vmcnt(0)). LDS rows 128B (8x16B segs), XOR swizzle seg^(row&7):
// ds_read_b128 bank-uniform, 0 conflicts (verified r6). 4 waves in 2x2.
// Work comes from the XCD-aware flat table: blockIdx.x -> (ct, e, row0);
// blocks of expert e have ids = e (mod 8) -> one XCD per expert, B+A slices
// L2-resident.
//   IS_FC:  A = x_bf gathered via entry list (row = entry>>1), out = gelu ->
//           hmid[base[e]+slot][ND] (slot-compacted, so GEMM2 reads it dense)
//   !IS_FC: A = hmid[base[e]+row] contiguous, out = atomicAdd(gate * acc)
template<int KD, int ND, int TN, bool IS_FC>
__global__ __launch_bounds__(256) void moe_gemm(
    const unsigned short* __restrict__ Asrc,
    const unsigned short* __restrict__ Bsrc,    // [E][ND][KD] (B^T form)
    const int* __restrict__ counts,
    const int* __restrict__ bases,
    const int* __restrict__ work,
    const int* __restrict__ entries,
    const float* __restrict__ gates,
    unsigned short* __restrict__ hmid,
    float* __restrict__ outp)
{
    constexpr int AJ = TN / 32;        // col frags per wave (4 or 2)
    constexpr int CB = TN / 32;        // B staging calls per thread (4 or 2)
    int pk = work[blockIdx.x];
    if (pk < 0) return;
    int ct   = pk >> 20;
    int e    = (pk >> 16) & 0xF;
    int row0 = pk & 0xFFFF;
    int n_e  = counts[e];
    int ebase = bases[e];
    int n0 = ct * TN;

    __shared__ __align__(16) unsigned short sA[128 * 64];
    __shared__ __align__(16) unsigned short sB[TN * 64];

    int tid = threadIdx.x;
    int w = tid >> 6;          // wave 0..3
    int l = tid & 63;          // lane
    const int* lst = entries + e * TOKENS;

    // ---- staging: rows are 128B (64 shorts), 8 segs of 16B. A call covers
    // 8 rows (64 lanes x 16B = 1KB). Global K-seg for (row r, LDS seg sg) is
    // sg ^ (r&7). Wave w stages A rows [w*32, w*32+32) (4 calls) and B rows
    // [w*(TN/4), ...) (CB calls).
    int sg = l & 7;
    int lr8 = l >> 3;                        // row-within-8 staged by this lane
    const unsigned short* Ag[4];
    int aLds[4];
#pragma unroll
    for (int c = 0; c < 4; c++) {
        int rr = w * 32 + c * 8 + lr8;       // tile row
        int gr = row0 + rr;
        int id = gr < n_e ? gr : n_e - 1;    // clamp (discarded in epilogue)
        size_t arow = IS_FC ? (size_t)(lst[id] >> 1) : (size_t)(ebase + id);
        Ag[c] = Asrc + arow * KD + (size_t)((sg ^ (rr & 7)) * 8);
        aLds[c] = (w * 32 + c * 8) * 64;     // wave-uniform chunk base (shorts)
    }
    const unsigned short* Bg[CB];
    int bLds[CB];
#pragma unroll
    for (int c = 0; c < CB; c++) {
        int rr = w * (TN / 4) + c * 8 + lr8;
        Bg[c] = Bsrc + ((size_t)e * ND + n0 + rr) * KD + (size_t)((sg ^ (rr & 7)) * 8);
        bLds[c] = (w * (TN / 4) + c * 8) * 64;
    }

    // ---- fragment addressing: lane (lo,q); sub-step s reads K-seg s*4+q of
    // row m at stored seg (s*4+q)^(m&7).
    int lo = l & 15;
    int q  = l >> 4;
    int wr = w >> 1, wc = w & 1;
    int aOff[4][2], bOff[AJ][2];
#pragma unroll
    for (int i = 0; i < 4; i++) {
        int m = wr * 64 + i * 16 + lo;
#pragma unroll
        for (int s = 0; s < 2; s++)
            aOff[i][s] = m * 64 + ((s * 4 + q) ^ (m & 7)) * 8;
    }
#pragma unroll
    for (int j = 0; j < AJ; j++) {
        int n = wc * (TN / 2) + j * 16 + lo;
#pragma unroll
        for (int s = 0; s < 2; s++)
            bOff[j][s] = n * 64 + ((s * 4 + q) ^ (n & 7)) * 8;
    }

    f32x4 acc[4][AJ];
#pragma unroll
    for (int i = 0; i < 4; i++)
#pragma unroll
        for (int j = 0; j < AJ; j++) acc[i][j] = (f32x4){0.f, 0.f, 0.f, 0.f};

    for (int k0 = 0; k0 < KD; k0 += 64) {
#pragma unroll
        for (int c = 0; c < 4; c++) gload_lds16(Ag[c] + k0, sA + aLds[c]);
#pragma unroll
        for (int c = 0; c < CB; c++) gload_lds16(Bg[c] + k0, sB + bLds[c]);
        __syncthreads();                    // drains vmcnt (compiler-inserted)
#pragma unroll
        for (int s = 0; s < 2; s++) {
            bf16x8 a[4], b[AJ];
#pragma unroll
            for (int i = 0; i < 4; i++) a[i] = *(const bf16x8*)(sA + aOff[i][s]);
#pragma unroll
            for (int j = 0; j < AJ; j++) b[j] = *(const bf16x8*)(sB + bOff[j][s]);
#pragma unroll
            for (int i = 0; i < 4; i++)
#pragma unroll
                for (int j = 0; j < AJ; j++)
                    acc[i][j] = __builtin_amdgcn_mfma_f32_16x16x32_bf16(a[i], b[j], acc[i][j], 0, 0, 0);
        }
        __syncthreads();                    // protect LDS before next staging
    }

    // ---- epilogue (D: col=lo, row=q*4+rr)
#pragma unroll
    for (int i = 0; i < 4; i++) {
        int rowB = row0 + wr * 64 + i * 16 + q * 4;
#pragma unroll
        for (int rr = 0; rr < 4; rr++) {
            int orow = rowB + rr;
            if (orow < n_e) {
                if (IS_FC) {
                    size_t hrow = (size_t)(ebase + orow);
#pragma unroll
                    for (int j = 0; j < AJ; j++) {
                        float v = acc[i][j][rr];
                        v = 0.5f * v * (1.f + erff(v * 0.70710678118654752f));  // exact gelu
                        hmid[hrow * ND + n0 + wc * (TN / 2) + j * 16 + lo] = f2bf(v);
                    }
                } else {
                    int token = lst[orow] >> 1;
                    float g = gates[e * TOKENS + orow];
#pragma unroll
                    for (int j = 0; j < AJ; j++) {
                        atomicAdd(&outp[(size_t)token * ND + n0 + wc * (TN / 2) + j * 16 + lo],
                                  acc[i][j][rr] * g);
                    }
                }
            }
        }
    }
}

// ---------------------------------------------------------------------------
extern "C" void kernel_launch(void* const* d_in, const int* in_sizes, int n_in,
                              void* d_out, int out_size, void* d_ws, size_t ws_size,
                              hipStream_t stream) {
    const float* x     = (const float*)d_in[0];   // [T, H]
    const float* gw    = (const float*)d_in[1];   // [E, H]
    const float* wfc   = (const float*)d_in[2];   // [E, FF, H]
    const float* wproj = (const float*)d_in[3];   // [E, H, FF]
    float* outp   = (float*)d_out;                       // [T*H]
    float* logits = outp + (size_t)TOKENS * HDIM;        // [T*E]

    char* ws = (char*)d_ws;
    int*   counts  = (int*)ws;                            // 8 ints
    int*   bases   = (int*)(ws + 64);                     // 8 ints
    int*   work    = (int*)(ws + 128);                    // [8*WMAX] ints
    int*   entries = (int*)(ws + 128 + 8 * WMAX * 4);     // [E][T]
    float* gates   = (float*)(ws + 128 + 8 * WMAX * 4 + NEXP * TOKENS * 4);
    size_t off = 128 + 8 * WMAX * 4 + 2ull * NEXP * TOKENS * 4;
    int*   tok_e   = (int*)(ws + off);   off += (size_t)TOKENS * 2 * 4;
    float* tok_g   = (float*)(ws + off); off += (size_t)TOKENS * 2 * 4;
    unsigned short* x_bf   = (unsigned short*)(ws + off); off += (size_t)TOKENS * HDIM * 2;
    unsigned short* wfc_bf = (unsigned short*)(ws + off); off += (size_t)NEXP * FFDIM * HDIM * 2;
    unsigned short* wpj_bf = (unsigned short*)(ws + off); off += (size_t)NEXP * HDIM * FFDIM * 2;
    unsigned short* hmid   = (unsigned short*)(ws + off);        // [2T][FF] bf16, slot-compacted

    cast_bf16_2<<<2048, 256, 0, stream>>>(wfc, wfc_bf, wproj, wpj_bf,
                                          NEXP * FFDIM * HDIM / 4);
    gating<<<TOKENS / 4, 256, 0, stream>>>(x, gw, logits, tok_e, tok_g, x_bf, outp);
    build_lists<<<1, 1024, 0, stream>>>(tok_e, tok_g, counts, bases, work,
                                        entries, gates);
    moe_gemm<HDIM, FFDIM, 128, true ><<<8 * WMAX, 256, 0, stream>>>(
        x_bf, wfc_bf, counts, bases, work, entries, gates, hmid, outp);
    moe_gemm<FFDIM, HDIM, 64, false><<<8 * WMAX, 256, 0, stream>>>(
        hmid, wpj_bf, counts, bases, work, entries, gates, hmid, outp);
}

// Round 8
// 234.513 us; speedup vs baseline: 1.3856x; 1.3856x over previous
//
#include <hip/hip_runtime.h>
#include <hip/hip_bf16.h>
#include <math.h>
#include <stdint.h>

// Problem constants (B=2, S=2048 -> T=4096 tokens)
#define TOKENS 4096
#define HDIM   768
#define FFDIM  1536
#define NEXP   8
#define NCT    12     // col tiles: GEMM1 1536/128, GEMM2 768/64 (same count!)
#define WMAX   768    // bucket capacity: worst case one expert owns all rows
#define GEMM_GRID 768 // 96 blocks per bucket; id%8 = bucket -> XCD affinity

typedef __attribute__((ext_vector_type(8))) short bf16x8;   // 8 bf16 = 4 VGPRs
typedef __attribute__((ext_vector_type(4))) float f32x4;    // MFMA accumulator

// round-to-nearest-even f32 -> bf16 (bit pattern)
__device__ __forceinline__ unsigned short f2bf(float f) {
    union { float f; uint32_t u; } c; c.f = f;
    uint32_t u = c.u;
    uint32_t r = (u + 0x7FFFu + ((u >> 16) & 1u)) >> 16;
    return (unsigned short)r;
}

// async global->LDS, 16B per lane; LDS dest is wave-uniform base + lane*16
__device__ __forceinline__ void gload_lds16(const void* g, void* l) {
    __builtin_amdgcn_global_load_lds(
        (const __attribute__((address_space(1))) void*)g,
        (__attribute__((address_space(3))) void*)l, 16, 0, 0);
}

// ---------------------------------------------------------------------------
// both weight casts in one dispatch; n4 = float4 count of EACH tensor
__global__ void cast_bf16_2(const float* __restrict__ s1, unsigned short* __restrict__ d1,
                            const float* __restrict__ s2, unsigned short* __restrict__ d2,
                            int n4) {
    int stride = gridDim.x * blockDim.x;
    for (int i = blockIdx.x * blockDim.x + threadIdx.x; i < 2 * n4; i += stride) {
        const float4* s = (i < n4) ? (const float4*)s1 : (const float4*)s2;
        ushort4* d = (i < n4) ? (ushort4*)d1 : (ushort4*)d2;
        int j = (i < n4) ? i : i - n4;
        float4 v = s[j];
        ushort4 o;
        o.x = f2bf(v.x); o.y = f2bf(v.y); o.z = f2bf(v.z); o.w = f2bf(v.w);
        d[j] = o;
    }
}

// ---------------------------------------------------------------------------
// Gating: one wave per token (4 tokens / 256-thread block). fp32 logits
// (checked output!), top-2 softmax, no atomics. Fused: bf16 cast of x, and
// zeroing of outp (must precede GEMM2, which is stream-ordered after).
__global__ __launch_bounds__(256) void gating(
    const float* __restrict__ x, const float* __restrict__ gw,
    float* __restrict__ logits,
    int* __restrict__ tok_e, float* __restrict__ tok_g,
    unsigned short* __restrict__ x_bf, float* __restrict__ outp)
{
    // zero outp: 786432 float4 over 1024 blocks = 3 per thread
    float4 zz = make_float4(0.f, 0.f, 0.f, 0.f);
#pragma unroll
    for (int j = 0; j < 3; j++)
        ((float4*)outp)[blockIdx.x * 768 + j * 256 + threadIdx.x] = zz;

    int t = blockIdx.x * 4 + (threadIdx.x >> 6);
    int lane = threadIdx.x & 63;
    const float4* xt = (const float4*)(x + (size_t)t * HDIM);   // 192 float4/token
    const float4* gw4 = (const float4*)gw;                      // [E][192]
    ushort4* xbt = (ushort4*)(x_bf + (size_t)t * HDIM);
    float acc[NEXP];
#pragma unroll
    for (int e = 0; e < NEXP; e++) acc[e] = 0.f;
#pragma unroll
    for (int it = 0; it < 3; it++) {
        int i = lane + it * 64;
        float4 xv = xt[i];
        ushort4 o;
        o.x = f2bf(xv.x); o.y = f2bf(xv.y); o.z = f2bf(xv.z); o.w = f2bf(xv.w);
        xbt[i] = o;
#pragma unroll
        for (int e = 0; e < NEXP; e++) {
            float4 wv = gw4[e * 192 + i];
            acc[e] += xv.x * wv.x + xv.y * wv.y + xv.z * wv.z + xv.w * wv.w;
        }
    }
#pragma unroll
    for (int e = 0; e < NEXP; e++) {
#pragma unroll
        for (int off = 32; off > 0; off >>= 1)
            acc[e] += __shfl_xor(acc[e], off);
    }
    if (lane == 0) {
        float4 l0 = make_float4(acc[0], acc[1], acc[2], acc[3]);
        float4 l1 = make_float4(acc[4], acc[5], acc[6], acc[7]);
        float4* lp = (float4*)(logits + (size_t)t * NEXP);
        lp[0] = l0; lp[1] = l1;
        int i0 = 0; float v0 = acc[0];
#pragma unroll
        for (int e = 1; e < NEXP; e++) if (acc[e] > v0) { v0 = acc[e]; i0 = e; }
        int i1 = -1; float v1 = -3.4e38f;
#pragma unroll
        for (int e = 0; e < NEXP; e++) if (e != i0 && acc[e] > v1) { v1 = acc[e]; i1 = e; }
        float g0 = 1.f / (1.f + expf(v1 - v0));   // softmax over top-2 (v0 >= v1)
        tok_e[t * 2] = i0; tok_e[t * 2 + 1] = i1;
        tok_g[t * 2] = g0; tok_g[t * 2 + 1] = 1.f - g0;
    }
}

// ---------------------------------------------------------------------------
// Build per-expert routed lists deterministically (no global atomics).
// Single block, 1024 threads (16 waves), 8 (token,k) entries per thread.
// Per-wave __shfl_up u64 scan + 16-wave fixup.
// Work table (XCD-aware): bucket b == expert e; slot p of bucket b lives at
// work[p*8+b]; fill[b] = rts_e * NCT. Table entries are written IN PARALLEL
// by 96 threads (one per (e,ct) pair) — r7's tid==0 serial build was 115 µs
// of dependent global stores. GEMM blocks stride the bucket (no sentinel,
// no overflow case: p is bounded by fill[b]).
__global__ __launch_bounds__(1024) void build_lists(
    const int* __restrict__ tok_e, const float* __restrict__ tok_g,
    int* __restrict__ counts, int* __restrict__ bases, int* __restrict__ fill,
    int* __restrict__ work,
    int* __restrict__ entries, float* __restrict__ gates)
{
    __shared__ unsigned long long wlo[16], whi[16];
    __shared__ int scnt[8];
    int tid = threadIdx.x;
    int lane = tid & 63, wid = tid >> 6;

    int eL[8]; float gL[8];
    int4 ea = ((const int4*)tok_e)[tid * 2];
    int4 eb = ((const int4*)tok_e)[tid * 2 + 1];
    float4 ga = ((const float4*)tok_g)[tid * 2];
    float4 gb = ((const float4*)tok_g)[tid * 2 + 1];
    eL[0] = ea.x; eL[1] = ea.y; eL[2] = ea.z; eL[3] = ea.w;
    eL[4] = eb.x; eL[5] = eb.y; eL[6] = eb.z; eL[7] = eb.w;
    gL[0] = ga.x; gL[1] = ga.y; gL[2] = ga.z; gL[3] = ga.w;
    gL[4] = gb.x; gL[5] = gb.y; gL[6] = gb.z; gL[7] = gb.w;

    unsigned long long clo = 0, chi = 0;
#pragma unroll
    for (int j = 0; j < 8; j++) {
        int e = eL[j];
        unsigned long long one = 1ull << ((e & 3) * 16);
        if (e < 4) clo += one; else chi += one;
    }
    unsigned long long ilo = clo, ihi = chi;
#pragma unroll
    for (int s = 1; s < 64; s <<= 1) {
        unsigned long long t1 = __shfl_up(ilo, s);
        unsigned long long t2 = __shfl_up(ihi, s);
        if (lane >= s) { ilo += t1; ihi += t2; }
    }
    if (lane == 63) { wlo[wid] = ilo; whi[wid] = ihi; }
    __syncthreads();
    if (tid == 0) {
        unsigned long long rl = 0, rh = 0;
#pragma unroll
        for (int i = 0; i < 16; i++) {
            unsigned long long a = wlo[i], b = whi[i];
            wlo[i] = rl; whi[i] = rh;   // exclusive wave prefix
            rl += a; rh += b;
        }
        int c[8];
#pragma unroll
        for (int e = 0; e < 4; e++) {
            c[e]     = (int)((rl >> (e * 16)) & 0xFFFF);
            c[e + 4] = (int)((rh >> (e * 16)) & 0xFFFF);
        }
        int b = 0;
#pragma unroll
        for (int e = 0; e < NEXP; e++) {
            scnt[e] = c[e]; counts[e] = c[e]; bases[e] = b; b += c[e];
            fill[e] = ((c[e] + 127) >> 7) * NCT;
        }
    }
    __syncthreads();
    // parallel work-table writers: thread (e, ct), e=tid/12, ct=tid%12
    if (tid < NEXP * NCT) {
        int e = tid / NCT, ct = tid % NCT;
        int rts = (scnt[e] + 127) >> 7;
        for (int r = 0; r < rts; r++)
            work[(ct * rts + r) * 8 + e] = (ct << 20) | (e << 16) | (r << 7);
    }
    unsigned long long rlo = wlo[wid] + (ilo - clo);   // exclusive thread prefix
    unsigned long long rhi = whi[wid] + (ihi - chi);
#pragma unroll
    for (int j = 0; j < 8; j++) {
        int e = eL[j];
        int sh = (e & 3) * 16;
        unsigned long long one = 1ull << sh;
        int slot;
        if (e < 4) { slot = (int)((rlo >> sh) & 0xFFFF); rlo += one; }
        else       { slot = (int)((rhi >> sh) & 0xFFFF); rhi += one; }
        entries[e * TOKENS + slot] = tid * 8 + j;   // = t*2+k
        gates[e * TOKENS + slot]   = gL[j];
    }
}

// ---------------------------------------------------------------------------
// Routed GEMM, 128xTN tile, BK=64, single-buffer 2-barrier K-loop (r5 dbuf
// regressed: dynamic buffer index defeats LDS alias analysis -> early
// vmcnt(0)). LDS rows 128B (8x16B segs), XOR swizzle seg^(row&7):
// ds_read_b128 bank-uniform, 0 conflicts (verified r6). 4 waves in 2x2.
// PERSISTENT blocks: bucket b = blockIdx.x%8 (= expert, XCD-affine under
// round-robin dispatch); block strides slots p = blockIdx.x/8, +96. All
// blocks of expert e on one XCD -> B slice + A rows (~4-5.5 MB) L2-resident.
//   IS_FC:  A = x_bf gathered via entry list (row = entry>>1), out = gelu ->
//           hmid[base[e]+slot][ND] (slot-compacted, so GEMM2 reads it dense)
//   !IS_FC: A = hmid[base[e]+row] contiguous, out = atomicAdd(gate * acc)
template<int KD, int ND, int TN, bool IS_FC>
__global__ __launch_bounds__(256) void moe_gemm(
    const unsigned short* __restrict__ Asrc,
    const unsigned short* __restrict__ Bsrc,    // [E][ND][KD] (B^T form)
    const int* __restrict__ counts,
    const int* __restrict__ bases,
    const int* __restrict__ fill,
    const int* __restrict__ work,
    const int* __restrict__ entries,
    const float* __restrict__ gates,
    unsigned short* __restrict__ hmid,
    float* __restrict__ outp)
{
    constexpr int AJ = TN / 32;        // col frags per wave (4 or 2)
    constexpr int CB = TN / 32;        // B staging calls per thread (4 or 2)
    int bkt = blockIdx.x & 7;
    int nfill = fill[bkt];

    int tid = threadIdx.x;
    int w = tid >> 6;          // wave 0..3
    int l = tid & 63;          // lane
    int sg = l & 7;
    int lr8 = l >> 3;          // row-within-8 staged by this lane
    int lo = l & 15;
    int q  = l >> 4;
    int wr = w >> 1, wc = w & 1;

    __shared__ __align__(16) unsigned short sA[128 * 64];
    __shared__ __align__(16) unsigned short sB[TN * 64];

    // fragment LDS offsets (item-independent)
    int aOff[4][2], bOff[AJ][2];
#pragma unroll
    for (int i = 0; i < 4; i++) {
        int m = wr * 64 + i * 16 + lo;
#pragma unroll
        for (int s = 0; s < 2; s++)
            aOff[i][s] = m * 64 + ((s * 4 + q) ^ (m & 7)) * 8;
    }
#pragma unroll
    for (int j = 0; j < AJ; j++) {
        int n = wc * (TN / 2) + j * 16 + lo;
#pragma unroll
        for (int s = 0; s < 2; s++)
            bOff[j][s] = n * 64 + ((s * 4 + q) ^ (n & 7)) * 8;
    }

    for (int p = blockIdx.x >> 3; p < nfill; p += GEMM_GRID / 8) {
        int pk   = work[p * 8 + bkt];
        int ct   = pk >> 20;
        int e    = (pk >> 16) & 0xF;
        int row0 = pk & 0xFFFF;
        int n_e  = counts[e];
        int ebase = bases[e];
        int n0 = ct * TN;
        const int* lst = entries + e * TOKENS;

        // ---- staging addresses: rows are 128B (64 shorts), 8 segs of 16B.
        // A call covers 8 rows (64 lanes x 16B = 1KB). Global K-seg for
        // (row r, LDS seg sg) is sg ^ (r&7). Wave w stages A rows
        // [w*32, w*32+32) (4 calls) and B rows [w*(TN/4), ...) (CB calls).
        const unsigned short* Ag[4];
        int aLds[4];
#pragma unroll
        for (int c = 0; c < 4; c++) {
            int rr = w * 32 + c * 8 + lr8;       // tile row
            int gr = row0 + rr;
            int id = gr < n_e ? gr : n_e - 1;    // clamp (discarded in epilogue)
            size_t arow = IS_FC ? (size_t)(lst[id] >> 1) : (size_t)(ebase + id);
            Ag[c] = Asrc + arow * KD + (size_t)((sg ^ (rr & 7)) * 8);
            aLds[c] = (w * 32 + c * 8) * 64;     // wave-uniform chunk base
        }
        const unsigned short* Bg[CB];
        int bLds[CB];
#pragma unroll
        for (int c = 0; c < CB; c++) {
            int rr = w * (TN / 4) + c * 8 + lr8;
            Bg[c] = Bsrc + ((size_t)e * ND + n0 + rr) * KD + (size_t)((sg ^ (rr & 7)) * 8);
            bLds[c] = (w * (TN / 4) + c * 8) * 64;
        }

        f32x4 acc[4][AJ];
#pragma unroll
        for (int i = 0; i < 4; i++)
#pragma unroll
            for (int j = 0; j < AJ; j++) acc[i][j] = (f32x4){0.f, 0.f, 0.f, 0.f};

        for (int k0 = 0; k0 < KD; k0 += 64) {
#pragma unroll
            for (int c = 0; c < 4; c++) gload_lds16(Ag[c] + k0, sA + aLds[c]);
#pragma unroll
            for (int c = 0; c < CB; c++) gload_lds16(Bg[c] + k0, sB + bLds[c]);
            __syncthreads();                    // drains vmcnt (compiler-inserted)
#pragma unroll
            for (int s = 0; s < 2; s++) {
                bf16x8 a[4], b[AJ];
#pragma unroll
                for (int i = 0; i < 4; i++) a[i] = *(const bf16x8*)(sA + aOff[i][s]);
#pragma unroll
                for (int j = 0; j < AJ; j++) b[j] = *(const bf16x8*)(sB + bOff[j][s]);
#pragma unroll
                for (int i = 0; i < 4; i++)
#pragma unroll
                    for (int j = 0; j < AJ; j++)
                        acc[i][j] = __builtin_amdgcn_mfma_f32_16x16x32_bf16(a[i], b[j], acc[i][j], 0, 0, 0);
            }
            __syncthreads();                    // protect LDS before next staging
        }

        // ---- epilogue (D: col=lo, row=q*4+rr)
#pragma unroll
        for (int i = 0; i < 4; i++) {
            int rowB = row0 + wr * 64 + i * 16 + q * 4;
#pragma unroll
            for (int rr = 0; rr < 4; rr++) {
                int orow = rowB + rr;
                if (orow < n_e) {
                    if (IS_FC) {
                        size_t hrow = (size_t)(ebase + orow);
#pragma unroll
                        for (int j = 0; j < AJ; j++) {
                            float v = acc[i][j][rr];
                            v = 0.5f * v * (1.f + erff(v * 0.70710678118654752f));  // exact gelu
                            hmid[hrow * ND + n0 + wc * (TN / 2) + j * 16 + lo] = f2bf(v);
                        }
                    } else {
                        int token = lst[orow] >> 1;
                        float g = gates[e * TOKENS + orow];
#pragma unroll
                        for (int j = 0; j < AJ; j++) {
                            atomicAdd(&outp[(size_t)token * ND + n0 + wc * (TN / 2) + j * 16 + lo],
                                      acc[i][j][rr] * g);
                        }
                    }
                }
            }
        }
    }
}

// ---------------------------------------------------------------------------
extern "C" void kernel_launch(void* const* d_in, const int* in_sizes, int n_in,
                              void* d_out, int out_size, void* d_ws, size_t ws_size,
                              hipStream_t stream) {
    const float* x     = (const float*)d_in[0];   // [T, H]
    const float* gw    = (const float*)d_in[1];   // [E, H]
    const float* wfc   = (const float*)d_in[2];   // [E, FF, H]
    const float* wproj = (const float*)d_in[3];   // [E, H, FF]
    float* outp   = (float*)d_out;                       // [T*H]
    float* logits = outp + (size_t)TOKENS * HDIM;        // [T*E]

    char* ws = (char*)d_ws;
    int*   counts  = (int*)ws;                            // 8 ints
    int*   bases   = (int*)(ws + 64);                     // 8 ints
    int*   fill    = (int*)(ws + 128);                    // 8 ints
    int*   work    = (int*)(ws + 256);                    // [WMAX*8] ints
    size_t off = 256 + (size_t)WMAX * 8 * 4;
    int*   entries = (int*)(ws + off);                    // [E][T]
    float* gates   = (float*)(ws + off + NEXP * TOKENS * 4);
    off += 2ull * NEXP * TOKENS * 4;
    int*   tok_e   = (int*)(ws + off);   off += (size_t)TOKENS * 2 * 4;
    float* tok_g   = (float*)(ws + off); off += (size_t)TOKENS * 2 * 4;
    unsigned short* x_bf   = (unsigned short*)(ws + off); off += (size_t)TOKENS * HDIM * 2;
    unsigned short* wfc_bf = (unsigned short*)(ws + off); off += (size_t)NEXP * FFDIM * HDIM * 2;
    unsigned short* wpj_bf = (unsigned short*)(ws + off); off += (size_t)NEXP * HDIM * FFDIM * 2;
    unsigned short* hmid   = (unsigned short*)(ws + off);        // [2T][FF] bf16, slot-compacted

    cast_bf16_2<<<2048, 256, 0, stream>>>(wfc, wfc_bf, wproj, wpj_bf,
                                          NEXP * FFDIM * HDIM / 4);
    gating<<<TOKENS / 4, 256, 0, stream>>>(x, gw, logits, tok_e, tok_g, x_bf, outp);
    build_lists<<<1, 1024, 0, stream>>>(tok_e, tok_g, counts, bases, fill, work,
                                        entries, gates);
    moe_gemm<HDIM, FFDIM, 128, true ><<<GEMM_GRID, 256, 0, stream>>>(
        x_bf, wfc_bf, counts, bases, fill, work, entries, gates, hmid, outp);
    moe_gemm<FFDIM, HDIM, 64, false><<<GEMM_GRID, 256, 0, stream>>>(
        hmid, wpj_bf, counts, bases, fill, work, entries, gates, hmid, outp);
}